// Round 1
// baseline (225.371 us; speedup 1.0000x reference)
//
#include <hip/hip_runtime.h>

#define M_DIM 16384
#define N_DIM 1024
#define K_DIM 4096

typedef __attribute__((ext_vector_type(4))) float f32x4;
typedef __attribute__((ext_vector_type(8))) short bf16x8;
typedef __attribute__((ext_vector_type(8))) unsigned short u16x8;

static __device__ __forceinline__ short f2bf(float f) {
  union { __bf16 h; short s; } u;
  u.h = (__bf16)f;   // RNE cvt; compiler packs pairs into v_cvt_pk_bf16_f32
  return u.s;
}

static __device__ __forceinline__ void load_lds16(const void* g, void* l) {
  __builtin_amdgcn_global_load_lds(
      (const __attribute__((address_space(1))) void*)g,
      (__attribute__((address_space(3))) void*)l, 16, 0, 0);
}

// ---------- prepass: WbT[n][k] = bf16(sign(W[k][n])) ----------
// sign -> bf16 is a pure bit-pattern select: +1 = 0x3F80, -1 = 0xBF80, 0 = 0
__global__ __launch_bounds__(256) void wsign_transpose(
    const float* __restrict__ W, unsigned short* __restrict__ WbT) {
  __shared__ unsigned short tile[64][72];  // +8 pad, rows 16B-aligned
  const int t  = (int)threadIdx.x;
  const int k0 = (int)(blockIdx.x >> 4) * 64;
  const int n0 = (int)(blockIdx.x & 15) * 64;
#pragma unroll
  for (int p = 0; p < 4; ++p) {
    const int r = p * 16 + (t >> 4);
    const int c = (t & 15) * 4;
    const float* src = W + (size_t)(k0 + r) * N_DIM + n0 + c;
#pragma unroll
    for (int j = 0; j < 4; ++j) {
      const float w = src[j];
      tile[r][c + j] = (w > 0.f) ? (unsigned short)0x3F80u
                                 : ((w < 0.f) ? (unsigned short)0xBF80u
                                              : (unsigned short)0u);
    }
  }
  __syncthreads();
  const int n  = t >> 2;
  const int kg = (t & 3) * 16;
  u16x8 o0, o1;
#pragma unroll
  for (int j = 0; j < 8; ++j) o0[j] = tile[kg + j][n];
#pragma unroll
  for (int j = 0; j < 8; ++j) o1[j] = tile[kg + 8 + j][n];
  unsigned short* dst = WbT + (size_t)(n0 + n) * K_DIM + k0 + kg;
  *(u16x8*)dst       = o0;
  *(u16x8*)(dst + 8) = o1;
}

// ---------- main GEMM: Z = X(fp32->bf16) @ WbT^T + sign(bias) ----------
// 128x128 tile, BK=64, 4 waves (2x2), each wave 4x4 frags of 16x16x32 MFMA.
// A kept fp32 in LDS (global_load_lds direct from X), cvt to bf16 at frag load.
// 16B-granule XOR swizzle on both tiles: linear LDS dest, pre-swizzled global
// source, swizzled read (involution) -> even 8 dwords/bank on ds_read_b128.
#define BM 128
#define BN 128
#define BK 64

__global__ __launch_bounds__(256) void gemm_bin(
    const float* __restrict__ X, const unsigned short* __restrict__ WbT,
    const float* __restrict__ bias, float* __restrict__ Z) {
  __shared__ __align__(16) float          As[BM * BK];  // 32 KiB
  __shared__ __align__(16) unsigned short Bs[BN * BK];  // 16 KiB

  const int t   = (int)threadIdx.x;
  const int l   = t & 63;
  const int wid = t >> 6;
  const int wm  = wid >> 1;  // 0..1
  const int wn  = wid & 1;   // 0..1

  // XCD-bijective swizzle (1024 blocks, %8==0); n-fastest -> A-panel L2 reuse
  const int bid = (int)blockIdx.x;
  const int swz = (bid & 7) * 128 + (bid >> 3);
  const int m0  = (swz >> 3) * BM;  // 0..127 tiles
  const int n0  = (swz & 7) * BN;   // 0..7 tiles

  // ---- LDS read offsets (constant over kt, all static-indexed) ----
  int aoff[2][4][2];
  int boff[2][4];
#pragma unroll
  for (int s = 0; s < 2; ++s) {
#pragma unroll
    for (int mi = 0; mi < 4; ++mi) {
      const int r  = wm * 64 + mi * 16 + (l & 15);
      const int g0 = s * 8 + (l >> 4) * 2;   // 16B granule of first 4 floats
      aoff[s][mi][0] = r * 64 + ((g0 ^ (r & 15)) << 2);
      aoff[s][mi][1] = r * 64 + (((g0 + 1) ^ (r & 15)) << 2);
    }
#pragma unroll
    for (int ni = 0; ni < 4; ++ni) {
      const int n = wn * 64 + ni * 16 + (l & 15);
      const int g = s * 4 + (l >> 4);        // 16B granule (8 bf16)
      boff[s][ni] = n * 64 + ((g ^ (n & 7)) << 3);
    }
  }

  // ---- staging addresses: linear LDS dest, inverse-swizzled global src ----
  const float* asrc[8];
  int adst[8];
#pragma unroll
  for (int i = 0; i < 8; ++i) {
    const int c = i * 256 + t;          // 16B chunk id, linear in lane
    const int r = c >> 4, gp = c & 15;
    const int g = gp ^ (r & 15);
    asrc[i] = X + (size_t)(m0 + r) * K_DIM + g * 4;
    adst[i] = c * 4;
  }
  const unsigned short* bsrc[4];
  int bdst[4];
#pragma unroll
  for (int i = 0; i < 4; ++i) {
    const int c = i * 256 + t;
    const int n = c >> 3, gp = c & 7;
    const int g = gp ^ (n & 7);
    bsrc[i] = WbT + (size_t)(n0 + n) * K_DIM + g * 8;
    bdst[i] = c * 8;
  }

  f32x4 acc[4][4] = {};

  for (int kt = 0; kt < K_DIM; kt += BK) {
#pragma unroll
    for (int i = 0; i < 8; ++i) load_lds16(asrc[i] + kt, As + adst[i]);
#pragma unroll
    for (int i = 0; i < 4; ++i) load_lds16(bsrc[i] + kt, Bs + bdst[i]);
    __syncthreads();  // compiler drains vmcnt(0) before s_barrier

#pragma unroll
    for (int s = 0; s < 2; ++s) {
      bf16x8 bfrag[4];
#pragma unroll
      for (int ni = 0; ni < 4; ++ni)
        bfrag[ni] = *(const bf16x8*)(Bs + boff[s][ni]);
#pragma unroll
      for (int mi = 0; mi < 4; ++mi) {
        const f32x4 a0 = *(const f32x4*)(As + aoff[s][mi][0]);
        const f32x4 a1 = *(const f32x4*)(As + aoff[s][mi][1]);
        bf16x8 af;
        af[0] = f2bf(a0[0]); af[1] = f2bf(a0[1]);
        af[2] = f2bf(a0[2]); af[3] = f2bf(a0[3]);
        af[4] = f2bf(a1[0]); af[5] = f2bf(a1[1]);
        af[6] = f2bf(a1[2]); af[7] = f2bf(a1[3]);
#pragma unroll
        for (int ni = 0; ni < 4; ++ni)
          acc[mi][ni] = __builtin_amdgcn_mfma_f32_16x16x32_bf16(
              af, bfrag[ni], acc[mi][ni], 0, 0, 0);
      }
    }
    __syncthreads();
  }

  // ---- epilogue: + sign(bias), store (D: col = lane&15, row = (lane>>4)*4+j)
#pragma unroll
  for (int ni = 0; ni < 4; ++ni) {
    const int col = n0 + wn * 64 + ni * 16 + (l & 15);
    const float b  = bias[col];
    const float bs = (b > 0.f) ? 1.f : ((b < 0.f) ? -1.f : 0.f);
#pragma unroll
    for (int mi = 0; mi < 4; ++mi) {
      const int row = m0 + wm * 64 + mi * 16 + ((l >> 4) << 2);
#pragma unroll
      for (int j = 0; j < 4; ++j)
        Z[(size_t)(row + j) * N_DIM + col] = acc[mi][ni][j] + bs;
    }
  }
}

// ---------- slow-but-correct fallback (only if ws too small) ----------
__global__ __launch_bounds__(256) void naive_fb(
    const float* __restrict__ X, const float* __restrict__ W,
    const float* __restrict__ bias, float* __restrict__ Z) {
  const size_t id = (size_t)blockIdx.x * 256 + threadIdx.x;
  const int m = (int)(id >> 10), n = (int)(id & 1023);
  float acc = 0.f;
  for (int k = 0; k < K_DIM; ++k) {
    const float w = W[(size_t)k * N_DIM + n];
    const float s = (w > 0.f) ? 1.f : ((w < 0.f) ? -1.f : 0.f);
    acc += X[(size_t)m * K_DIM + k] * s;
  }
  const float b = bias[n];
  Z[id] = acc + ((b > 0.f) ? 1.f : ((b < 0.f) ? -1.f : 0.f));
}

extern "C" void kernel_launch(void* const* d_in, const int* in_sizes, int n_in,
                              void* d_out, int out_size, void* d_ws, size_t ws_size,
                              hipStream_t stream) {
  const float* X    = (const float*)d_in[0];
  const float* W    = (const float*)d_in[1];
  const float* bias = (const float*)d_in[2];
  float* Z = (float*)d_out;

  const size_t need = (size_t)N_DIM * K_DIM * sizeof(unsigned short);  // 8 MiB
  if (ws_size >= need) {
    unsigned short* WbT = (unsigned short*)d_ws;
    wsign_transpose<<<dim3((K_DIM / 64) * (N_DIM / 64)), dim3(256), 0, stream>>>(W, WbT);
    gemm_bin<<<dim3((M_DIM / BM) * (N_DIM / BN)), dim3(256), 0, stream>>>(X, WbT, bias, Z);
  } else {
    naive_fb<<<dim3((size_t)M_DIM * N_DIM / 256), dim3(256), 0, stream>>>(X, W, bias, Z);
  }
}

// Round 2
// 191.987 us; speedup vs baseline: 1.1739x; 1.1739x over previous
//
#include <hip/hip_runtime.h>

#define M_DIM 16384
#define N_DIM 1024
#define K_DIM 4096

#define BM 256
#define BN 256
#define BK 64
#define NT (K_DIM / BK)

typedef __attribute__((ext_vector_type(4))) float f32x4;
typedef __attribute__((ext_vector_type(8))) short bf16x8;
typedef __attribute__((ext_vector_type(8))) unsigned short u16x8;

static __device__ __forceinline__ short f2bf(float f) {
  union { __bf16 h; short s; } u;
  u.h = (__bf16)f;   // RNE; compiler packs pairs into v_cvt_pk_bf16_f32
  return u.s;
}

static __device__ __forceinline__ void load_lds16(const void* g, void* l) {
  __builtin_amdgcn_global_load_lds(
      (const __attribute__((address_space(1))) void*)g,
      (__attribute__((address_space(3))) void*)l, 16, 0, 0);
}

// ---------- prepass: WbT[n][k] = bf16(sign(W[k][n])) ----------
__global__ __launch_bounds__(256) void wsign_transpose(
    const float* __restrict__ W, unsigned short* __restrict__ WbT) {
  __shared__ unsigned short tile[64][72];
  const int t  = (int)threadIdx.x;
  const int k0 = (int)(blockIdx.x >> 4) * 64;
  const int n0 = (int)(blockIdx.x & 15) * 64;
#pragma unroll
  for (int p = 0; p < 4; ++p) {
    const int r = p * 16 + (t >> 4);
    const int c = (t & 15) * 4;
    const float* src = W + (size_t)(k0 + r) * N_DIM + n0 + c;
#pragma unroll
    for (int j = 0; j < 4; ++j) {
      const float w = src[j];
      tile[r][c + j] = (w > 0.f) ? (unsigned short)0x3F80u
                                 : ((w < 0.f) ? (unsigned short)0xBF80u
                                              : (unsigned short)0u);
    }
  }
  __syncthreads();
  const int n  = t >> 2;
  const int kg = (t & 3) * 16;
  u16x8 o0, o1;
#pragma unroll
  for (int j = 0; j < 8; ++j) o0[j] = tile[kg + j][n];
#pragma unroll
  for (int j = 0; j < 8; ++j) o1[j] = tile[kg + 8 + j][n];
  unsigned short* dst = WbT + (size_t)(n0 + n) * K_DIM + k0 + kg;
  *(u16x8*)dst       = o0;
  *(u16x8*)(dst + 8) = o1;
}

// ---------- main GEMM: 256x256 tile, BK=64, 8 waves (2x4), dbuf LDS ----------
// A: X fp32 -> reg -> cvt bf16 -> swizzled ds_write_b128 (T14 split staging)
// B: WbT bf16 via global_load_lds w16, pre-swizzled global source (rule #21)
// Both tiles: 16B-granule XOR swizzle (gran ^= row&7) -> conflict-free b128.
__global__ __launch_bounds__(512, 2) void gemm_bin(
    const float* __restrict__ X, const unsigned short* __restrict__ WbT,
    const float* __restrict__ bias, float* __restrict__ Z) {
  __shared__ __align__(16) unsigned short As[2][BM * BK];  // 64 KiB
  __shared__ __align__(16) unsigned short Bs[2][BN * BK];  // 64 KiB

  const int t   = (int)threadIdx.x;
  const int l   = t & 63;
  const int wid = t >> 6;
  const int wm  = wid >> 2;  // 0..1 -> row half
  const int wn  = wid & 3;   // 0..3 -> col quarter

  // XCD-bijective swizzle: 256 blocks, 32/XCD, n-fastest within XCD
  const int bid = (int)blockIdx.x;
  const int swz = (bid & 7) * 32 + (bid >> 3);
  const int m0  = (swz >> 2) * BM;  // 64 m-tiles
  const int n0  = (swz & 3) * BN;   // 4 n-tiles

  // ---- fragment read offsets (ushort units). row&7 == l&7 for all mi/ni ----
  const int abase = (wm * 128 + (l & 15)) * BK;
  const int bbase = (wn * 64 + (l & 15)) * BK;
  const int axk0  = (((l >> 4) + 0) ^ (l & 7)) << 3;
  const int axk1  = (((l >> 4) + 4) ^ (l & 7)) << 3;

  // ---- A staging: thread owns 4 dest 16B-granules (8 bf16 each) ----
  const float* a_src[4];
  int a_dst[4];
#pragma unroll
  for (int i = 0; i < 4; ++i) {
    const int d = i * 512 + t;        // dest granule id, linear in thread
    const int row = d >> 3, g = d & 7;
    a_src[i] = X + (size_t)(m0 + row) * K_DIM + g * 8;      // 8 floats
    a_dst[i] = row * BK + ((g ^ (row & 7)) << 3);           // swizzled dest
  }
  // ---- B staging: linear LDS dest, inverse-swizzled global source ----
  const unsigned short* b_src[4];
  int b_dst[4];
#pragma unroll
  for (int i = 0; i < 4; ++i) {
    const int c = i * 512 + t;
    const int n = c >> 3, gp = c & 7;
    b_src[i] = WbT + (size_t)(n0 + n) * K_DIM + (gp ^ (n & 7)) * 8;
    b_dst[i] = c * 8;
  }

  f32x4 acc[8][4] = {};
  f32x4 areg[4][2];

#define STAGE_A_LOAD(KT)                                                  \
  {                                                                       \
    _Pragma("unroll") for (int i = 0; i < 4; ++i) {                       \
      areg[i][0] = *(const f32x4*)(a_src[i] + (KT));                      \
      areg[i][1] = *(const f32x4*)(a_src[i] + (KT) + 4);                  \
    }                                                                     \
  }
#define STAGE_A_WRITE(BUF)                                                \
  {                                                                       \
    _Pragma("unroll") for (int i = 0; i < 4; ++i) {                       \
      u16x8 v;                                                            \
      _Pragma("unroll") for (int j = 0; j < 4; ++j) {                     \
        v[j]     = (unsigned short)f2bf(areg[i][0][j]);                   \
        v[4 + j] = (unsigned short)f2bf(areg[i][1][j]);                   \
      }                                                                   \
      *(u16x8*)(&As[BUF][a_dst[i]]) = v;                                  \
    }                                                                     \
  }
#define STAGE_B(KT, BUF)                                                  \
  {                                                                       \
    _Pragma("unroll") for (int i = 0; i < 4; ++i)                         \
      load_lds16(b_src[i] + (KT), &Bs[BUF][b_dst[i]]);                    \
  }
#define COMPUTE(CUR)                                                      \
  {                                                                       \
    const unsigned short* Ab = As[CUR];                                   \
    const unsigned short* Bb = Bs[CUR];                                   \
    _Pragma("unroll") for (int kk = 0; kk < 2; ++kk) {                    \
      const int axk = kk ? axk1 : axk0;                                   \
      bf16x8 bf[4];                                                       \
      _Pragma("unroll") for (int ni = 0; ni < 4; ++ni)                    \
        bf[ni] = *(const bf16x8*)(Bb + bbase + ni * 1024 + axk);          \
      _Pragma("unroll") for (int mi = 0; mi < 8; ++mi) {                  \
        const bf16x8 af = *(const bf16x8*)(Ab + abase + mi * 1024 + axk); \
        _Pragma("unroll") for (int ni = 0; ni < 4; ++ni)                  \
          acc[mi][ni] = __builtin_amdgcn_mfma_f32_16x16x32_bf16(          \
              af, bf[ni], acc[mi][ni], 0, 0, 0);                          \
      }                                                                   \
    }                                                                     \
  }

  // prologue: stage tile 0 into buffer 0
  STAGE_A_LOAD(0);
  STAGE_B(0, 0);
  STAGE_A_WRITE(0);
  __syncthreads();  // drains vmcnt (B-DMA) + lgkm (A writes)

  int cur = 0;
  for (int tt = 0; tt < NT - 1; ++tt) {
    const int ktn = (tt + 1) * BK;
    STAGE_A_LOAD(ktn);      // issue early: HBM latency hides under MFMA
    STAGE_B(ktn, cur ^ 1);  // DMA into the other buffer
    COMPUTE(cur);
    STAGE_A_WRITE(cur ^ 1); // write late (after compute), just before barrier
    __syncthreads();        // one barrier per K-tile
    cur ^= 1;
  }
  COMPUTE(cur);  // last tile, no prefetch

  // ---- epilogue: + sign(bias); D frag: col = l&15, row = (l>>4)*4 + j ----
#pragma unroll
  for (int ni = 0; ni < 4; ++ni) {
    const int col = n0 + wn * 64 + ni * 16 + (l & 15);
    const float b  = bias[col];
    const float bs = (b > 0.f) ? 1.f : ((b < 0.f) ? -1.f : 0.f);
#pragma unroll
    for (int mi = 0; mi < 8; ++mi) {
      const int row = m0 + wm * 128 + mi * 16 + ((l >> 4) << 2);
#pragma unroll
      for (int j = 0; j < 4; ++j)
        Z[(size_t)(row + j) * N_DIM + col] = acc[mi][ni][j] + bs;
    }
  }
#undef STAGE_A_LOAD
#undef STAGE_A_WRITE
#undef STAGE_B
#undef COMPUTE
}

// ---------- slow-but-correct fallback (only if ws too small) ----------
__global__ __launch_bounds__(256) void naive_fb(
    const float* __restrict__ X, const float* __restrict__ W,
    const float* __restrict__ bias, float* __restrict__ Z) {
  const size_t id = (size_t)blockIdx.x * 256 + threadIdx.x;
  const int m = (int)(id >> 10), n = (int)(id & 1023);
  float acc = 0.f;
  for (int k = 0; k < K_DIM; ++k) {
    const float w = W[(size_t)k * N_DIM + n];
    const float s = (w > 0.f) ? 1.f : ((w < 0.f) ? -1.f : 0.f);
    acc += X[(size_t)m * K_DIM + k] * s;
  }
  const float b = bias[n];
  Z[id] = acc + ((b > 0.f) ? 1.f : ((b < 0.f) ? -1.f : 0.f));
}

extern "C" void kernel_launch(void* const* d_in, const int* in_sizes, int n_in,
                              void* d_out, int out_size, void* d_ws, size_t ws_size,
                              hipStream_t stream) {
  const float* X    = (const float*)d_in[0];
  const float* W    = (const float*)d_in[1];
  const float* bias = (const float*)d_in[2];
  float* Z = (float*)d_out;

  const size_t need = (size_t)N_DIM * K_DIM * sizeof(unsigned short);  // 8 MiB
  if (ws_size >= need) {
    unsigned short* WbT = (unsigned short*)d_ws;
    wsign_transpose<<<dim3((K_DIM / 64) * (N_DIM / 64)), dim3(256), 0, stream>>>(W, WbT);
    gemm_bin<<<dim3((M_DIM / BM) * (N_DIM / BN)), dim3(512), 0, stream>>>(X, WbT, bias, Z);
  } else {
    naive_fb<<<dim3((size_t)M_DIM * N_DIM / 256), dim3(256), 0, stream>>>(X, W, bias, Z);
  }
}

// Round 3
// 188.371 us; speedup vs baseline: 1.1964x; 1.0192x over previous
//
#include <hip/hip_runtime.h>

#define M_DIM 16384
#define N_DIM 1024
#define K_DIM 4096

#define BM 256
#define BN 256
#define BK 64
#define NT (K_DIM / BK)

typedef __attribute__((ext_vector_type(4))) float f32x4;
typedef __attribute__((ext_vector_type(8))) short bf16x8;
typedef __attribute__((ext_vector_type(8))) unsigned short u16x8;

static __device__ __forceinline__ short f2bf(float f) {
  union { __bf16 h; short s; } u;
  u.h = (__bf16)f;   // RNE; pairs pack into v_cvt_pk_bf16_f32
  return u.s;
}

static __device__ __forceinline__ void load_lds16(const void* g, void* l) {
  __builtin_amdgcn_global_load_lds(
      (const __attribute__((address_space(1))) void*)g,
      (__attribute__((address_space(3))) void*)l, 16, 0, 0);
}

// ---------- prepass: WbT[n][k] = bf16(sign(W[k][n])) ----------
__global__ __launch_bounds__(256) void wsign_transpose(
    const float* __restrict__ W, unsigned short* __restrict__ WbT) {
  __shared__ unsigned short tile[64][72];
  const int t  = (int)threadIdx.x;
  const int k0 = (int)(blockIdx.x >> 4) * 64;
  const int n0 = (int)(blockIdx.x & 15) * 64;
#pragma unroll
  for (int p = 0; p < 4; ++p) {
    const int r = p * 16 + (t >> 4);
    const int c = (t & 15) * 4;
    const float* src = W + (size_t)(k0 + r) * N_DIM + n0 + c;
#pragma unroll
    for (int j = 0; j < 4; ++j) {
      const float w = src[j];
      tile[r][c + j] = (w > 0.f) ? (unsigned short)0x3F80u
                                 : ((w < 0.f) ? (unsigned short)0xBF80u
                                              : (unsigned short)0u);
    }
  }
  __syncthreads();
  const int n  = t >> 2;
  const int kg = (t & 3) * 16;
  u16x8 o0, o1;
#pragma unroll
  for (int j = 0; j < 8; ++j) o0[j] = tile[kg + j][n];
#pragma unroll
  for (int j = 0; j < 8; ++j) o1[j] = tile[kg + 8 + j][n];
  unsigned short* dst = WbT + (size_t)(n0 + n) * K_DIM + k0 + kg;
  *(u16x8*)dst       = o0;
  *(u16x8*)(dst + 8) = o1;
}

// ---------- main GEMM: 256x256, BK=64, 8 waves, 4-phase counted-vmcnt ----------
__global__ __launch_bounds__(512, 2) void gemm_bin(
    const float* __restrict__ X, const unsigned short* __restrict__ WbT,
    const float* __restrict__ bias, float* __restrict__ Z) {
  __shared__ __align__(16) unsigned short As[2][BM * BK];  // 64 KiB
  __shared__ __align__(16) unsigned short Bs[2][BN * BK];  // 64 KiB

  const int t   = (int)threadIdx.x;
  const int l   = t & 63;
  const int wid = t >> 6;
  const int wm  = wid >> 2;  // 0..1
  const int wn  = wid & 3;   // 0..3

  const int bid = (int)blockIdx.x;
  const int swz = (bid & 7) * 32 + (bid >> 3);  // bijective: 256 = 8*32
  const int m0  = (swz >> 2) * BM;
  const int n0  = (swz & 3) * BN;

  const int abase = (wm * 128 + (l & 15)) * BK;
  const int bbase = (wn * 64 + (l & 15)) * BK;
  const int axk0  = (((l >> 4) + 0) ^ (l & 7)) << 3;
  const int axk1  = (((l >> 4) + 4) ^ (l & 7)) << 3;

  // A staging: 4 dest granules/thread; swizzled dest, linear source
  const float* a_src[4];
  int a_dst[4];
#pragma unroll
  for (int i = 0; i < 4; ++i) {
    const int d = i * 512 + t;
    const int row = d >> 3, g = d & 7;
    a_src[i] = X + (size_t)(m0 + row) * K_DIM + g * 8;
    a_dst[i] = row * BK + ((g ^ (row & 7)) << 3);
  }
  // B staging: linear LDS dest, inverse-swizzled global source
  const unsigned short* b_src[4];
  int b_dst[4];
#pragma unroll
  for (int i = 0; i < 4; ++i) {
    const int c = i * 512 + t;
    const int n = c >> 3, gp = c & 7;
    b_src[i] = WbT + (size_t)(n0 + n) * K_DIM + (gp ^ (n & 7)) * 8;
    b_dst[i] = c * 8;
  }

  f32x4 acc[8][4] = {};
  f32x4 areg[4][2];
  bf16x8 aF[2][4], bN0[2][2], bN1[2][2];

#define SB0 __builtin_amdgcn_sched_barrier(0)
#define BAR do { SB0; __builtin_amdgcn_s_barrier(); SB0; } while (0)
#define WVM(N) do { asm volatile("s_waitcnt vmcnt(" #N ")" ::: "memory"); SB0; } while (0)
#define WLG do { asm volatile("s_waitcnt lgkmcnt(0)" ::: "memory"); SB0; } while (0)
#define PRIO1 __builtin_amdgcn_s_setprio(1)
#define PRIO0 __builtin_amdgcn_s_setprio(0)

#define ISSUE_A(KT)                                                        \
  do { SB0;                                                                \
    _Pragma("unroll") for (int i = 0; i < 4; ++i) {                        \
      areg[i][0] = *(const f32x4*)(a_src[i] + (KT));                       \
      areg[i][1] = *(const f32x4*)(a_src[i] + (KT) + 4);                   \
    } SB0;                                                                 \
  } while (0)
#define WRITE_A(BUF)                                                       \
  do {                                                                     \
    _Pragma("unroll") for (int i = 0; i < 4; ++i) {                        \
      u16x8 v;                                                             \
      _Pragma("unroll") for (int j = 0; j < 4; ++j) {                      \
        v[j]     = (unsigned short)f2bf(areg[i][0][j]);                    \
        v[4 + j] = (unsigned short)f2bf(areg[i][1][j]);                    \
      }                                                                    \
      *(u16x8*)(&As[BUF][a_dst[i]]) = v;                                   \
    }                                                                      \
  } while (0)
#define ISSUE_B(KT, BUF)                                                   \
  do { SB0;                                                                \
    _Pragma("unroll") for (int i = 0; i < 4; ++i)                          \
      load_lds16(b_src[i] + (KT), &Bs[BUF][b_dst[i]]);                     \
    SB0;                                                                   \
  } while (0)
#define READ_A(MH, AB)                                                     \
  do {                                                                     \
    _Pragma("unroll") for (int mi = 0; mi < 4; ++mi) {                     \
      aF[0][mi] = *(const bf16x8*)((AB) + abase + ((MH)*4 + mi) * 1024 + axk0); \
      aF[1][mi] = *(const bf16x8*)((AB) + abase + ((MH)*4 + mi) * 1024 + axk1); \
    }                                                                      \
  } while (0)
#define READ_B(NH, DST, BB)                                                \
  do {                                                                     \
    _Pragma("unroll") for (int ni = 0; ni < 2; ++ni) {                     \
      DST[0][ni] = *(const bf16x8*)((BB) + bbase + ((NH)*2 + ni) * 1024 + axk0); \
      DST[1][ni] = *(const bf16x8*)((BB) + bbase + ((NH)*2 + ni) * 1024 + axk1); \
    }                                                                      \
  } while (0)
#define MFMA_Q(MH, NH, BF)                                                 \
  do {                                                                     \
    _Pragma("unroll") for (int kk = 0; kk < 2; ++kk)                       \
      _Pragma("unroll") for (int mi = 0; mi < 4; ++mi)                     \
        _Pragma("unroll") for (int ni = 0; ni < 2; ++ni)                   \
          acc[(MH)*4 + mi][(NH)*2 + ni] =                                  \
              __builtin_amdgcn_mfma_f32_16x16x32_bf16(                     \
                  aF[kk][mi], BF[kk][ni], acc[(MH)*4 + mi][(NH)*2 + ni],   \
                  0, 0, 0);                                                \
  } while (0)

  // ---- prologue: stage tiles 0 and 1; issue order fixed: A0,B0,A1,B1 ----
  ISSUE_A(0);
  ISSUE_B(0, 0);
  WVM(4);          // A0 arrived (B0 still in flight)
  WRITE_A(0);
  ISSUE_A(BK);
  ISSUE_B(BK, 1);
  WVM(12);         // B0 arrived (A1:8 + B1:4 remain)
  WLG;
  BAR;

  // ---- steady state: t = 0 .. NT-3 ----
  for (int tt = 0; tt <= NT - 3; ++tt) {
    const int buf = tt & 1;
    const unsigned short* Ab = As[buf];
    const unsigned short* Bb = Bs[buf];
    // P0: retire A(t+1) regs -> LDS(buf^1); frags mh0/nh0; MFMA q00
    WVM(4);
    WRITE_A(buf ^ 1);
    READ_A(0, Ab);
    READ_B(0, bN0, Bb);
    BAR; WLG;
    PRIO1; MFMA_Q(0, 0, bN0); PRIO0;
    BAR;
    // P1: issue A(t+2) global loads; frags nh1; MFMA q01
    ISSUE_A((tt + 2) * BK);
    READ_B(1, bN1, Bb);
    BAR; WLG;
    PRIO1; MFMA_Q(0, 1, bN1); PRIO0;
    BAR;
    // P2: issue B(t+2) DMA into buf (B-region reads retired at P1 barrier)
    ISSUE_B((tt + 2) * BK, buf);
    READ_A(1, Ab);
    BAR; WLG;
    PRIO1; MFMA_Q(1, 1, bN1); PRIO0;
    BAR;
    // P3: MFMA q10; then require B(t+1) DMA done before publishing barrier
    PRIO1; MFMA_Q(1, 0, bN0); PRIO0;
    WVM(12);       // oldest 4 = B(t+1); keeps A(t+2)+B(t+2) = 12 in flight
    BAR;
  }

  // ---- tail tile NT-2 (no new issues) ----
  {
    const int buf = (NT - 2) & 1;
    const unsigned short* Ab = As[buf];
    const unsigned short* Bb = Bs[buf];
    WVM(4);
    WRITE_A(buf ^ 1);   // A(NT-1) -> other buf
    READ_A(0, Ab);
    READ_B(0, bN0, Bb);
    BAR; WLG;
    PRIO1; MFMA_Q(0, 0, bN0); PRIO0;
    BAR;
    READ_B(1, bN1, Bb);
    BAR; WLG;
    PRIO1; MFMA_Q(0, 1, bN1); PRIO0;
    BAR;
    READ_A(1, Ab);
    BAR; WLG;
    PRIO1; MFMA_Q(1, 1, bN1); PRIO0;
    BAR;
    PRIO1; MFMA_Q(1, 0, bN0); PRIO0;
    WVM(0);             // B(NT-1) DMA done
    BAR;
  }
  // ---- last tile NT-1: straight-line (compiler inserts lgkm waits) ----
  {
    const int buf = (NT - 1) & 1;
    const unsigned short* Ab = As[buf];
    const unsigned short* Bb = Bs[buf];
    READ_A(0, Ab);
    READ_B(0, bN0, Bb);
    READ_B(1, bN1, Bb);
    MFMA_Q(0, 0, bN0);
    MFMA_Q(0, 1, bN1);
    READ_A(1, Ab);
    MFMA_Q(1, 1, bN1);
    MFMA_Q(1, 0, bN0);
  }

  // ---- epilogue: + sign(bias); D frag: col = l&15, row = (l>>4)*4 + j ----
#pragma unroll
  for (int ni = 0; ni < 4; ++ni) {
    const int col = n0 + wn * 64 + ni * 16 + (l & 15);
    const float b  = bias[col];
    const float bs = (b > 0.f) ? 1.f : ((b < 0.f) ? -1.f : 0.f);
#pragma unroll
    for (int mi = 0; mi < 8; ++mi) {
      const int row = m0 + wm * 128 + mi * 16 + ((l >> 4) << 2);
#pragma unroll
      for (int j = 0; j < 4; ++j)
        Z[(size_t)(row + j) * N_DIM + col] = acc[mi][ni][j] + bs;
    }
  }
#undef SB0
#undef BAR
#undef WVM
#undef WLG
#undef PRIO1
#undef PRIO0
#undef ISSUE_A
#undef WRITE_A
#undef ISSUE_B
#undef READ_A
#undef READ_B
#undef MFMA_Q
}

// ---------- slow-but-correct fallback (only if ws too small) ----------
__global__ __launch_bounds__(256) void naive_fb(
    const float* __restrict__ X, const float* __restrict__ W,
    const float* __restrict__ bias, float* __restrict__ Z) {
  const size_t id = (size_t)blockIdx.x * 256 + threadIdx.x;
  const int m = (int)(id >> 10), n = (int)(id & 1023);
  float acc = 0.f;
  for (int k = 0; k < K_DIM; ++k) {
    const float w = W[(size_t)k * N_DIM + n];
    const float s = (w > 0.f) ? 1.f : ((w < 0.f) ? -1.f : 0.f);
    acc += X[(size_t)m * K_DIM + k] * s;
  }
  const float b = bias[n];
  Z[id] = acc + ((b > 0.f) ? 1.f : ((b < 0.f) ? -1.f : 0.f));
}

extern "C" void kernel_launch(void* const* d_in, const int* in_sizes, int n_in,
                              void* d_out, int out_size, void* d_ws, size_t ws_size,
                              hipStream_t stream) {
  const float* X    = (const float*)d_in[0];
  const float* W    = (const float*)d_in[1];
  const float* bias = (const float*)d_in[2];
  float* Z = (float*)d_out;

  const size_t need = (size_t)N_DIM * K_DIM * sizeof(unsigned short);  // 8 MiB
  if (ws_size >= need) {
    unsigned short* WbT = (unsigned short*)d_ws;
    wsign_transpose<<<dim3((K_DIM / 64) * (N_DIM / 64)), dim3(256), 0, stream>>>(W, WbT);
    gemm_bin<<<dim3((M_DIM / BM) * (N_DIM / BN)), dim3(512), 0, stream>>>(X, WbT, bias, Z);
  } else {
    naive_fb<<<dim3((size_t)M_DIM * N_DIM / 256), dim3(256), 0, stream>>>(X, W, bias, Z);
  }
}